// Round 4
// baseline (306.972 us; speedup 1.0000x reference)
//
#include <hip/hip_runtime.h>

// Soft differentiable rasterizer, forward only. THREE-kernel structure.
// R12 -> R13 post-mortem: R12's scalar-side coef pipeline could not fit
// (2x40 floats > ~102 SGPRs; SGPR_Count stayed 64) -> compiler sank the
// prefetch loads (no pipelining) and kept rotation moves (VGPR 16->24,
// VALUBusy 72% but dur 155us). Setup fixes were neutral: setup is
// parallelism-starved (192 blocks on 256 CUs, 93KB LDS, 8 barrier phases),
// not conflict-bound.
// R13: (a) raster pipelines through VGPRs: coef pointer laundered via
//     empty asm (asm outputs are divergence-analysis-divergent) -> 10x
//     global_load_dwordx4 per slot into VGPRs, two NAMED buffers, unroll
//     x2 (no rotation moves). List word + coef loads for i+1/i+2 issue
//     before slot i's 12-exp2 chain; hardware vmcnt covers them. No LDS.
// (b) setup split: setup_a (192 x 256thr) per-frame prep -> g_coef/g_pq/
//     g_npos; setup_b (8 bands x 192 frames x 256thr, 20KB LDS) stages pq
//     (padded stride 18 float2 = b128-conflict-optimal), culls 16 rows,
//     mbcnt-compacts straight to g_list/g_cnt. 6 blocks/CU vs 0.75.
// Design (R8/R9): 32x2 px tiles, per-edge line-form interval cull,
// pos-first packing, packed-fp32 sigmoid product, front-to-back T,
// wave exit at T < 2e-3.

#define HH 128
#define WW 128
#define NN 128
#define KK 12
#define SAPB 256
#define SBPB 256
#define RTPB 256
#define STATE_SZ (NN * KK * 2 + NN) // 3200
#define CULL_U 15.0f
#define COEF_STRIDE 40              // floats per slot: A[12] B[12] C[12] gc[4]
#define PQ_LSTR 18                  // setup_b LDS float2 stride (36 words: b128-optimal)

typedef float f2 __attribute__((ext_vector_type(2)));

static __device__ inline f2 mk2(float a, float b) { f2 r; r.x = a; r.y = b; return r; }

// ---------------- setup_a: per-frame prep ----------------
__global__ __launch_bounds__(SAPB) void setup_a(
    const float* __restrict__ traj,
    const float* __restrict__ colors,
    const float* __restrict__ alpha,
    const float* __restrict__ zval,
    const void*  __restrict__ csg_raw,
    float* __restrict__ g_coef,         // [T][128][40]
    float2* __restrict__ g_pq,          // [T][128][12] pos-first packed
    int* __restrict__ g_npos)           // [T][128]
{
    __shared__ float s_state[STATE_SZ];                           // 12.8 KB
    __shared__ __align__(16) float s_coef[NN][COEF_STRIDE];       // 20.5 KB
    __shared__ __align__(16) float2 s_pq[NN][KK];                 // 12.3 KB
    __shared__ float s_orient[NN];
    __shared__ float s_z[NN];
    __shared__ int   s_slot2prim[NN];
    __shared__ int   s_npos[NN], s_nneg[NN];
    __shared__ int   s_mode;

    const int frame = blockIdx.x;
    const int tid   = threadIdx.x;
    const float* st = traj + (size_t)frame * STATE_SZ;

    // stage state (float4), csg layout detect (one-wave ballot), init
    for (int i = tid; i < STATE_SZ / 4; i += SAPB)
        ((float4*)s_state)[i] = ((const float4*)st)[i];
    if (tid < NN) { s_z[tid] = zval[tid]; s_npos[tid] = 0; s_nneg[tid] = 0; }
    if (tid < 64) {
        unsigned w = (tid < 32) ? ((const unsigned*)csg_raw)[tid] : 0u;
        unsigned long long anyw = __ballot(w > 1u);
        unsigned long long anyb = __ballot((w & 0xFEFEFEFEu) != 0u);
        if (tid == 0) s_mode = (anyw == 0ull) ? 0 : ((anyb == 0ull) ? 1 : 2);
    }
    __syncthreads();

    // per-prim: orient, g = alpha*sigmoid(alive), z-rank -> slot
    if (tid < NN) {
        const int n = tid;
        float area2 = 0.f;
        #pragma unroll
        for (int k = 0; k < KK; k++) {
            int k1 = (k + 1) % KK;
            float v0x = s_state[(n * KK + k)  * 2 + 0];
            float v0y = s_state[(n * KK + k)  * 2 + 1];
            float v1x = s_state[(n * KK + k1) * 2 + 0];
            float v1y = s_state[(n * KK + k1) * 2 + 1];
            area2 += v0x * v1y - v1x * v0y;
        }
        float orient = (area2 > 0.f) ? 1.f : ((area2 < 0.f) ? -1.f : 0.f);
        s_orient[n] = orient;

        float alive = s_state[NN * KK * 2 + n];
        float g = alpha[n] / (1.f + __expf(-alive));

        float zn = s_z[n];
        int rank = 0;
        #pragma unroll 8
        for (int j = 0; j < NN; j++) {
            float zj = s_z[j];
            rank += (zj < zn || (zj == zn && j < n)) ? 1 : 0;
        }
        int slot = (NN - 1) - rank; // slot 0 = frontmost (largest z)
        s_slot2prim[slot] = n;

        int mode = s_mode;
        int sub;
        if (mode == 0)      sub = ((const int*)csg_raw)[n] != 0;
        else if (mode == 1) sub = ((const unsigned char*)csg_raw)[n] != 0;
        else                sub = ((const float*)csg_raw)[n] != 0.f;
        float cs = sub ? 0.f : 1.f;
        s_coef[slot][36] = g;
        s_coef[slot][37] = colors[n * 3 + 0] * cs;
        s_coef[slot][38] = colors[n * 3 + 1] * cs;
        s_coef[slot][39] = colors[n * 3 + 2] * cs;
    }
    __syncthreads();

    // edge coefficients (slot-ordered SoA)
    const float QSCALE = 100.0f * 1.4426950408889634f;
    for (int idx = tid; idx < NN * KK; idx += SAPB) {
        int slot = idx / KK;
        int k    = idx - slot * KK;
        int n    = s_slot2prim[slot];
        int k1   = (k + 1) % KK;
        float v0x = s_state[(n * KK + k)  * 2 + 0];
        float v0y = s_state[(n * KK + k)  * 2 + 1];
        float v1x = s_state[(n * KK + k1) * 2 + 0];
        float v1y = s_state[(n * KK + k1) * 2 + 1];
        float ex = v1x - v0x, ey = v1y - v0y;
        float q  = -s_orient[n] * QSCALE;
        s_coef[slot][0  + k] = q * ex;                      // A
        s_coef[slot][12 + k] = -q * ey;                     // B
        s_coef[slot][24 + k] = -q * (ex * v0y - ey * v0x);  // C
    }
    __syncthreads();

    // line form per edge: x-constraint t(gy) = Q*gy + P. pos-first packing.
    const float SLACK = 0.01f;
    for (int idx = tid; idx < NN * KK; idx += SAPB) {
        int slot = idx / KK;
        int k    = idx - slot * KK;
        float A = s_coef[slot][k];
        float B = s_coef[slot][12 + k];
        float C = s_coef[slot][24 + k];
        float rcpB = __builtin_amdgcn_rcpf(B);
        float Praw = (CULL_U - C) * rcpB;
        float Qraw = -A * rcpB;
        if (B > 0.f) {
            int i = atomicAdd(&s_npos[slot], 1);
            s_pq[slot][i] = make_float2(Qraw, Praw + SLACK);
        } else if (B < 0.f) {
            int i = atomicAdd(&s_nneg[slot], 1);
            s_pq[slot][(KK - 1) - i] = make_float2(-Qraw, -Praw + SLACK);
        } else { // B == 0: x-independent edge; conservatively no constraint
            int i = atomicAdd(&s_nneg[slot], 1);
            s_pq[slot][(KK - 1) - i] = make_float2(0.f, 1e30f);
        }
    }
    __syncthreads();

    // copy out: coef (float4), pq (float4), npos
    {
        float4* dstc = (float4*)(g_coef + (size_t)frame * (NN * COEF_STRIDE));
        const float4* srcc = (const float4*)&s_coef[0][0];
        for (int i = tid; i < (NN * COEF_STRIDE) / 4; i += SAPB) dstc[i] = srcc[i];
        float4* dstp = (float4*)(g_pq + (size_t)frame * (NN * KK));
        const float4* srcp = (const float4*)&s_pq[0][0];
        for (int i = tid; i < (NN * KK) / 2; i += SAPB) dstp[i] = srcp[i];
        if (tid < NN) g_npos[frame * NN + tid] = s_npos[tid];
    }
}

// ---------------- setup_b: band cull + compaction ----------------
__global__ __launch_bounds__(SBPB) void setup_b(
    const float2* __restrict__ g_pq,
    const int* __restrict__ g_npos,
    int* __restrict__ g_cnt,            // [T][256]
    unsigned char* __restrict__ g_list) // [T][256][128]
{
    __shared__ __align__(16) float2 s_pqp[NN][PQ_LSTR];           // 18.4 KB
    __shared__ int s_np[NN];
    __shared__ unsigned long long s_qb[16][4][2];                 // 1 KB

    const int band  = blockIdx.x;   // 0..7 (16 rows each)
    const int frame = blockIdx.y;
    const int tid   = threadIdx.x;

    // stage pq into padded-stride LDS + npos
    const float2* pqf = g_pq + (size_t)frame * (NN * KK);
    for (int i = tid; i < NN * KK; i += SBPB) {
        int slot = i / KK, k = i - slot * KK;
        s_pqp[slot][k] = pqf[i];
    }
    if (tid < NN) s_np[tid] = g_npos[frame * NN + tid];
    __syncthreads();

    // interval cull over 16 rows x 128 slots; 4 x-quarter masks per row
    const float GX_LO = 0.5f / WW;
    const float GX_HI = (WW - 0.5f) / WW;
    for (int j = 0; j < (16 * NN) / SBPB; j++) {     // 8 iters
        int idx = j * SBPB + tid;
        int rl = idx >> 7, s = idx & (NN - 1);
        int row = band * 16 + rl;
        float gyr = (row + 0.5f) * (1.0f / HH);
        int npos = s_np[s];
        const float4* pq4 = (const float4*)&s_pqp[s][0];
        float y1 = 1e30f, y2 = 1e30f;
        #pragma unroll
        for (int h = 0; h < KK / 2; h++) {
            float4 v = pq4[h];                       // {Q,P,Q,P}
            int k0 = 2 * h, k1 = 2 * h + 1;
            float t0 = fmaf(v.x, gyr, v.y);
            float t1 = fmaf(v.z, gyr, v.w);
            bool p0 = k0 < npos, p1 = k1 < npos;
            y1 = fminf(y1, p0 ? t0 : 1e30f);
            y2 = fminf(y2, p0 ? 1e30f : t0);
            y1 = fminf(y1, p1 ? t1 : 1e30f);
            y2 = fminf(y2, p1 ? 1e30f : t1);
        }
        float xhi = fminf(y1, GX_HI);
        float xlo = fmaxf(-y2, GX_LO);
        bool ne = (xlo <= xhi);
        #pragma unroll
        for (int q = 0; q < 4; q++) {
            float qlo = (q * 32 + 0.5f) * (1.0f / WW);
            float qhi = (q * 32 + 31.5f) * (1.0f / WW);
            unsigned long long m = __ballot(ne && (xlo <= qhi) && (xhi >= qlo));
            if ((tid & 63) == 0) s_qb[rl][q][(s >= 64) ? 1 : 0] = m;
        }
    }
    __syncthreads();

    // compaction: wave w -> 8 local tiles; mbcnt prefix scatter to GLOBAL
    {
        int wvS = tid >> 6;
        int ln  = tid & 63;
        for (int it = 0; it < 8; it++) {
            int tl  = wvS * 8 + it;             // local tile 0..31
            int rpl = tl >> 2, qq = tl & 3;
            unsigned long long b0 = s_qb[2 * rpl][qq][0] | s_qb[2 * rpl + 1][qq][0];
            unsigned long long b1 = s_qb[2 * rpl][qq][1] | s_qb[2 * rpl + 1][qq][1];
            int gtile = band * 32 + tl;
            unsigned char* dst = g_list + ((size_t)frame * 256 + gtile) * NN;
            int c0 = __popcll(b0);
            int p0 = __builtin_amdgcn_mbcnt_hi((unsigned)(b0 >> 32),
                     __builtin_amdgcn_mbcnt_lo((unsigned)b0, 0));
            int p1 = __builtin_amdgcn_mbcnt_hi((unsigned)(b1 >> 32),
                     __builtin_amdgcn_mbcnt_lo((unsigned)b1, 0));
            if ((b0 >> ln) & 1ull) dst[p0]      = (unsigned char)ln;
            if ((b1 >> ln) & 1ull) dst[c0 + p1] = (unsigned char)(64 + ln);
            if (ln == 0) g_cnt[frame * 256 + gtile] = c0 + __popcll(b1);
        }
    }
}

// ---------------- raster ----------------
struct F3 { float x, y, z; };

// load 40 floats (one slot's coefs) as 10x global_load_dwordx4 into VGPRs.
// Pointer laundered through asm: uniformity analysis marks asm outputs
// divergent -> vector loads (VGPR data, hw-tracked vmcnt), NOT s_loads.
#define LOADQ(P, Q0,Q1,Q2,Q3,Q4,Q5,Q6,Q7,Q8,Q9)                         \
    { const float4* c4_ = (const float4*)(P);                           \
      asm("" : "+v"(c4_));                                              \
      Q0 = c4_[0]; Q1 = c4_[1]; Q2 = c4_[2]; Q3 = c4_[3]; Q4 = c4_[4];  \
      Q5 = c4_[5]; Q6 = c4_[6]; Q7 = c4_[7]; Q8 = c4_[8]; Q9 = c4_[9]; }

#define EDGE2(Af, Bf, Cf)                                               \
    { f2 u = __builtin_elementwise_fma(Bf, gx2,                         \
              __builtin_elementwise_fma(Af, gy2, Cf));                  \
      u = __builtin_elementwise_max(u, lo2);                            \
      f2 e; e.x = __builtin_amdgcn_exp2f(u.x);                          \
      e.y = __builtin_amdgcn_exp2f(u.y);                                \
      qv = __builtin_elementwise_fma(qv, e, qv); }

// A: Q0-Q2, B: Q3-Q5, C: Q6-Q8 (pairs via float4 subregs, no moves), gc: Q9
#define COMPUTE(Q0,Q1,Q2,Q3,Q4,Q5,Q6,Q7,Q8,Q9)                          \
    { f2 qv = mk2(1.f, 1.f);                                            \
      EDGE2(mk2(Q0.x,Q0.y), mk2(Q3.x,Q3.y), mk2(Q6.x,Q6.y));            \
      EDGE2(mk2(Q0.z,Q0.w), mk2(Q3.z,Q3.w), mk2(Q6.z,Q6.w));            \
      EDGE2(mk2(Q1.x,Q1.y), mk2(Q4.x,Q4.y), mk2(Q7.x,Q7.y));            \
      EDGE2(mk2(Q1.z,Q1.w), mk2(Q4.z,Q4.w), mk2(Q7.z,Q7.w));            \
      EDGE2(mk2(Q2.x,Q2.y), mk2(Q5.x,Q5.y), mk2(Q8.x,Q8.y));            \
      EDGE2(mk2(Q2.z,Q2.w), mk2(Q5.z,Q5.w), mk2(Q8.z,Q8.w));            \
      float cov = __builtin_amdgcn_rcpf(qv.x * qv.y);                   \
      float a = cov * Q9.x;                                             \
      float w = a * Tt;                                                 \
      rr = fmaf(w, Q9.y, rr); gg = fmaf(w, Q9.z, gg);                   \
      bb = fmaf(w, Q9.w, bb);                                           \
      Tt = fmaf(-a, Tt, Tt); }

__global__ __launch_bounds__(RTPB) void raster_kernel(
    const float* __restrict__ g_coef,
    const int* __restrict__ g_cnt,
    const unsigned char* __restrict__ g_list,
    float* __restrict__ out)
{
    const int tid   = threadIdx.x;
    const int wv    = tid >> 6;
    const int lane  = tid & 63;
    const int frame = blockIdx.y;
    const int tile  = blockIdx.x * 4 + wv;  // 0..255
    const int rp    = tile >> 2;            // row pair
    const int q     = tile & 3;             // x quarter

    const unsigned char* lst = g_list + ((size_t)frame * 256 + tile) * NN;
    const unsigned* lw = (const unsigned*)lst;
    const int cnt = g_cnt[frame * 256 + tile];

    const int lx  = lane & 31, ly = lane >> 5;
    const int px  = q * 32 + lx;
    const int row = rp * 2 + ly;
    const float gy = (row + 0.5f) * (1.0f / HH);
    const float gx = (px  + 0.5f) * (1.0f / WW);
    const f2 gy2 = mk2(gy, gy);
    const f2 gx2 = mk2(gx, gx);
    const f2 lo2 = mk2(-100.f, -100.f);     // exp2 underflow guard (inf*0=NaN)

    const float* cfr = g_coef + (size_t)frame * (NN * COEF_STRIDE);

    float Tt = 1.f, rr = 0.f, gg = 0.f, bb = 0.f;
    if (cnt > 0) {
        float4 A0,A1,A2,A3,A4,A5,A6,A7,A8,A9;
        float4 B0,B1,B2,B3,B4,B5,B6,B7,B8,B9;
        unsigned w0 = (unsigned)__builtin_amdgcn_readfirstlane((int)lw[0]);
        int sC = (int)(w0 & 0xFFu);                               // slot(0)
        int sN = (cnt > 1) ? (int)((w0 >> 8) & 0xFFu) : sC;       // slot(1)
        LOADQ(cfr + sC * COEF_STRIDE, A0,A1,A2,A3,A4,A5,A6,A7,A8,A9);
        int i = 0;
        for (;;) {
            // even half: compute bufA(slot i); prefetch bufB<-slot(i+1), list(i+2)
            {
                int ip2 = (i + 2 < cnt) ? i + 2 : cnt - 1;
                unsigned wrd = lw[ip2 >> 2];                       // issue early
                LOADQ(cfr + sN * COEF_STRIDE, B0,B1,B2,B3,B4,B5,B6,B7,B8,B9);
                COMPUTE(A0,A1,A2,A3,A4,A5,A6,A7,A8,A9);           // covers latency
                sN = (int)((((unsigned)__builtin_amdgcn_readfirstlane((int)wrd))
                            >> ((ip2 & 3) * 8)) & 0xFFu);
            }
            if (++i >= cnt || !__any(Tt > 2e-3f)) break;
            // odd half: compute bufB; prefetch bufA<-slot(i+1), list(i+2)
            {
                int ip2 = (i + 2 < cnt) ? i + 2 : cnt - 1;
                unsigned wrd = lw[ip2 >> 2];
                LOADQ(cfr + sN * COEF_STRIDE, A0,A1,A2,A3,A4,A5,A6,A7,A8,A9);
                COMPUTE(B0,B1,B2,B3,B4,B5,B6,B7,B8,B9);
                sN = (int)((((unsigned)__builtin_amdgcn_readfirstlane((int)wrd))
                            >> ((ip2 & 3) * 8)) & 0xFFu);
            }
            if (++i >= cnt || !__any(Tt > 2e-3f)) break;
        }
    }

    size_t o = ((size_t)frame * (HH * WW) + (size_t)row * WW + px) * 3;
    *(F3*)(out + o) = F3{rr, gg, bb};    // coalesced dwordx3 per row segment
}

extern "C" void kernel_launch(void* const* d_in, const int* in_sizes, int n_in,
                              void* d_out, int out_size, void* d_ws, size_t ws_size,
                              hipStream_t stream) {
    const float* traj   = (const float*)d_in[0];
    const float* colors = (const float*)d_in[1];
    const float* alpha  = (const float*)d_in[2];
    const float* zval   = (const float*)d_in[3];
    const void*  csg    = d_in[4];
    float* out = (float*)d_out;

    const int T = in_sizes[0] / STATE_SZ; // 192

    size_t coef_sz = (size_t)T * NN * COEF_STRIDE * sizeof(float); // 3.93 MB
    size_t cnt_sz  = (size_t)T * 256 * sizeof(int);                // 0.20 MB
    size_t list_sz = (size_t)T * 256 * NN;                         // 6.29 MB
    size_t pq_sz   = (size_t)T * NN * KK * sizeof(float2);         // 2.36 MB
    char* p = (char*)d_ws;
    float*         g_coef = (float*)p;          p += coef_sz;
    int*           g_cnt  = (int*)p;            p += cnt_sz;
    unsigned char* g_list = (unsigned char*)p;  p += list_sz;
    float2*        g_pq   = (float2*)p;         p += pq_sz;
    int*           g_npos = (int*)p;

    setup_a<<<T, SAPB, 0, stream>>>(traj, colors, alpha, zval, csg,
                                    g_coef, g_pq, g_npos);
    setup_b<<<dim3(8, T), SBPB, 0, stream>>>(g_pq, g_npos, g_cnt, g_list);
    dim3 grid(256 / 4, T); // 64 x 192, wave = one 32x2 tile
    raster_kernel<<<grid, RTPB, 0, stream>>>(g_coef, g_cnt, g_list, out);
}

// Round 5
// 208.366 us; speedup vs baseline: 1.4732x; 1.4732x over previous
//
#include <hip/hip_runtime.h>

// Soft differentiable rasterizer, forward only. Two-kernel structure.
// R13 -> R14 post-mortem: asm-laundered "VGPR pipeline" failed — loads are
// ordinary IR ops, scheduler sank buffer-B loads past COMPUTE-A (VGPR=36,
// not ~100), leaving unoverlapped VMEM latency per slot: 234us, VALUBusy
// 38%. Lesson: can't build a SW pipeline by issuing loads early in source;
// must reduce the NUMBER of stall points structurally.
// R14 = R9 raster (proven 131us) + TWO-SLOT BATCHING: both slots' 80
// uniform coef loads issue together, one lgkmcnt wait per PAIR (stall
// points halved: ~43us exposed latency -> ~21us predicted). Two
// independent qv chains double exp2/fma ILP. Compositing exact (cov0,cov1
// independent; T applied in order). Early-exit granularity 2.
// SGPR ~100/102: if it doesn't fit, compiler sinks slot-1 loads and we
// degrade to R9 behavior (downside ~0).
// Setup = R12's single-kernel (measured equal to split; pq padded stride
// 18 float2, mbcnt wave-cooperative compaction, ballot csg detect).
// Design (R8/R9): 32x2 px tiles, per-edge line-form interval cull,
// pos-first packing, packed-fp32 sigmoid product, front-to-back T,
// wave exit at T < 2e-3.

#define HH 128
#define WW 128
#define NN 128
#define KK 12
#define STPB 1024
#define RTPB 256
#define STATE_SZ (NN * KK * 2 + NN) // 3200
#define CULL_U 15.0f
#define COEF_STRIDE 40              // floats per slot: A[12] B[12] C[12] gc[4]
#define PQ_STRIDE 18                // float2 per slot (padded; 36 words, bank-optimal)

typedef float f2 __attribute__((ext_vector_type(2)));

__global__ __launch_bounds__(STPB) void setup_kernel(
    const float* __restrict__ traj,
    const float* __restrict__ colors,
    const float* __restrict__ alpha,
    const float* __restrict__ zval,
    const void*  __restrict__ csg_raw,
    float* __restrict__ g_coef,         // [T][128][40]
    int* __restrict__ g_cnt,            // [T][256]
    unsigned char* __restrict__ g_list) // [T][256][128]
{
    __shared__ __align__(16) float s_coef[NN][COEF_STRIDE];       // 20.5 KB
    __shared__ __align__(16) float2 s_pq[NN][PQ_STRIDE];          // 18 KB
    __shared__ float s_state[STATE_SZ];                           // 12.8 KB
    __shared__ float s_orient[NN];
    __shared__ float s_z[NN];
    __shared__ int   s_slot2prim[NN];
    __shared__ int   s_npos[NN], s_nneg[NN];
    __shared__ unsigned long long s_qbits[HH][4][2];              // 8 KB
    __shared__ unsigned char s_list[4 * (HH / 2)][NN];            // 32 KB
    __shared__ int s_cnt[4 * (HH / 2)];
    __shared__ int s_mode;

    const int frame = blockIdx.x;
    const int tid   = threadIdx.x;
    const float* st = traj + (size_t)frame * STATE_SZ;

    // ---- stage + csg layout detect (one-wave ballot) + counter init ----
    for (int i = tid; i < STATE_SZ; i += STPB) s_state[i] = st[i];
    if (tid < NN) { s_z[tid] = zval[tid]; s_npos[tid] = 0; s_nneg[tid] = 0; }
    if (tid < 64) {
        unsigned w = (tid < 32) ? ((const unsigned*)csg_raw)[tid] : 0u;
        unsigned long long anyw = __ballot(w > 1u);            // some word not 0/1
        unsigned long long anyb = __ballot((w & 0xFEFEFEFEu) != 0u); // some byte > 1
        if (tid == 0) s_mode = (anyw == 0ull) ? 0 : ((anyb == 0ull) ? 1 : 2);
    }
    __syncthreads();

    // ---- per-prim: orient, g = alpha*sigmoid(alive), z-rank -> slot ----
    if (tid < NN) {
        const int n = tid;
        float area2 = 0.f;
        #pragma unroll
        for (int k = 0; k < KK; k++) {
            int k1 = (k + 1) % KK;
            float v0x = s_state[(n * KK + k)  * 2 + 0];
            float v0y = s_state[(n * KK + k)  * 2 + 1];
            float v1x = s_state[(n * KK + k1) * 2 + 0];
            float v1y = s_state[(n * KK + k1) * 2 + 1];
            area2 += v0x * v1y - v1x * v0y;
        }
        float orient = (area2 > 0.f) ? 1.f : ((area2 < 0.f) ? -1.f : 0.f);
        s_orient[n] = orient;

        float alive = s_state[NN * KK * 2 + n];
        float g = alpha[n] / (1.f + __expf(-alive));

        float zn = s_z[n];
        int rank = 0;
        #pragma unroll 8
        for (int j = 0; j < NN; j++) {
            float zj = s_z[j];
            rank += (zj < zn || (zj == zn && j < n)) ? 1 : 0;
        }
        int slot = (NN - 1) - rank; // slot 0 = frontmost (largest z)
        s_slot2prim[slot] = n;

        int mode = s_mode;
        int sub;
        if (mode == 0)      sub = ((const int*)csg_raw)[n] != 0;
        else if (mode == 1) sub = ((const unsigned char*)csg_raw)[n] != 0;
        else                sub = ((const float*)csg_raw)[n] != 0.f;
        float cs = sub ? 0.f : 1.f;
        s_coef[slot][36] = g;
        s_coef[slot][37] = colors[n * 3 + 0] * cs;
        s_coef[slot][38] = colors[n * 3 + 1] * cs;
        s_coef[slot][39] = colors[n * 3 + 2] * cs;
    }
    __syncthreads();

    // ---- edge coefficients (slot-ordered SoA) ----
    const float QSCALE = 100.0f * 1.4426950408889634f;
    for (int idx = tid; idx < NN * KK; idx += STPB) {
        int slot = idx / KK;
        int k    = idx - slot * KK;
        int n    = s_slot2prim[slot];
        int k1   = (k + 1) % KK;
        float v0x = s_state[(n * KK + k)  * 2 + 0];
        float v0y = s_state[(n * KK + k)  * 2 + 1];
        float v1x = s_state[(n * KK + k1) * 2 + 0];
        float v1y = s_state[(n * KK + k1) * 2 + 1];
        float ex = v1x - v0x, ey = v1y - v0y;
        float q  = -s_orient[n] * QSCALE;
        s_coef[slot][0  + k] = q * ex;                      // A
        s_coef[slot][12 + k] = -q * ey;                     // B
        s_coef[slot][24 + k] = -q * (ex * v0y - ey * v0x);  // C
    }
    __syncthreads();

    // ---- line form per edge: x-constraint t(gy) = Q*gy + P ----
    // B>0: x <= t (+SLACK); B<0: x >= t (stored negated: -x <= -t, +SLACK);
    // B==0: no x-constraint -> neg-bucket entry with t' = +1e30 (never binds).
    // Pos edges packed first (k < npos). STRIDED LOOP (R8 bug: bare if).
    const float SLACK = 0.01f;
    for (int idx = tid; idx < NN * KK; idx += STPB) {
        int slot = idx / KK;
        int k    = idx - slot * KK;
        (void)k;
        float A = s_coef[slot][idx - slot * KK];
        float B = s_coef[slot][12 + (idx - slot * KK)];
        float C = s_coef[slot][24 + (idx - slot * KK)];
        float rcpB = __builtin_amdgcn_rcpf(B);
        float Praw = (CULL_U - C) * rcpB;
        float Qraw = -A * rcpB;
        if (B > 0.f) {
            int i = atomicAdd(&s_npos[slot], 1);
            s_pq[slot][i] = make_float2(Qraw, Praw + SLACK);
        } else if (B < 0.f) {
            int i = atomicAdd(&s_nneg[slot], 1);
            s_pq[slot][(KK - 1) - i] = make_float2(-Qraw, -Praw + SLACK);
        } else { // B == 0: x-independent edge; conservatively no constraint
            int i = atomicAdd(&s_nneg[slot], 1);
            s_pq[slot][(KK - 1) - i] = make_float2(0.f, 1e30f);
        }
    }
    __syncthreads();

    // ---- joint interval cull; 4 x-quarter keep masks per row ----
    // wave covers one row (r const) x 64 slots (s = s0 + lane).
    // s_pq slot stride = 36 words -> float4 reads conflict-optimal.
    const float GX_LO = 0.5f / WW;
    const float GX_HI = (WW - 0.5f) / WW;
    for (int j = 0; j < (HH * NN) / STPB; j++) {     // 16 iters
        int idx = j * STPB + tid;
        int r = idx >> 7, s = idx & (NN - 1);
        float gyr = (r + 0.5f) * (1.0f / HH);
        int npos = s_npos[s];
        const float4* pq4 = (const float4*)&s_pq[s][0];
        float y1 = 1e30f, y2 = 1e30f;
        #pragma unroll
        for (int h = 0; h < KK / 2; h++) {
            float4 v = pq4[h];                       // {Q,P,Q,P}
            int k0 = 2 * h, k1 = 2 * h + 1;
            float t0 = fmaf(v.x, gyr, v.y);
            float t1 = fmaf(v.z, gyr, v.w);
            bool p0 = k0 < npos, p1 = k1 < npos;
            y1 = fminf(y1, p0 ? t0 : 1e30f);
            y2 = fminf(y2, p0 ? 1e30f : t0);
            y1 = fminf(y1, p1 ? t1 : 1e30f);
            y2 = fminf(y2, p1 ? 1e30f : t1);
        }
        float xhi = fminf(y1, GX_HI);
        float xlo = fmaxf(-y2, GX_LO);
        bool ne = (xlo <= xhi);
        #pragma unroll
        for (int q = 0; q < 4; q++) {
            float qlo = (q * 32 + 0.5f) * (1.0f / WW);
            float qhi = (q * 32 + 31.5f) * (1.0f / WW);
            unsigned long long m = __ballot(ne && (xlo <= qhi) && (xhi >= qlo));
            if ((tid & 63) == 0) s_qbits[r][q][(s >= 64) ? 1 : 0] = m;
        }
    }
    __syncthreads();

    // ---- compaction: wave-cooperative mbcnt prefix scatter ----
    {
        int wvS = tid >> 6;
        int ln  = tid & 63;
        for (int it = 0; it < 16; it++) {
            int t = wvS * 16 + it;
            int rp = t >> 2, qq = t & 3;
            unsigned long long b0 = s_qbits[2 * rp][qq][0] | s_qbits[2 * rp + 1][qq][0];
            unsigned long long b1 = s_qbits[2 * rp][qq][1] | s_qbits[2 * rp + 1][qq][1];
            int c0 = __popcll(b0);
            int p0 = __builtin_amdgcn_mbcnt_hi((unsigned)(b0 >> 32),
                     __builtin_amdgcn_mbcnt_lo((unsigned)b0, 0));
            int p1 = __builtin_amdgcn_mbcnt_hi((unsigned)(b1 >> 32),
                     __builtin_amdgcn_mbcnt_lo((unsigned)b1, 0));
            if ((b0 >> ln) & 1ull) s_list[t][p0]      = (unsigned char)ln;
            if ((b1 >> ln) & 1ull) s_list[t][c0 + p1] = (unsigned char)(64 + ln);
            if (ln == 0) s_cnt[t] = c0 + __popcll(b1);
        }
    }
    __syncthreads();

    // ---- copy out ----
    {
        float* dstc = g_coef + (size_t)frame * (NN * COEF_STRIDE);
        const float* srcc = &s_coef[0][0];
        for (int i = tid; i < NN * COEF_STRIDE; i += STPB) dstc[i] = srcc[i];
        if (tid < 256) g_cnt[frame * 256 + tid] = s_cnt[tid];
        unsigned int* dstl = (unsigned int*)(g_list + (size_t)frame * (256 * NN));
        const unsigned int* srcl = (const unsigned int*)&s_list[0][0];
        for (int i = tid; i < (256 * NN) / 4; i += STPB) dstl[i] = srcl[i];
    }
}

struct F3 { float x, y, z; };

__global__ __launch_bounds__(RTPB) void raster_kernel(
    const float* __restrict__ g_coef,
    const int* __restrict__ g_cnt,
    const unsigned char* __restrict__ g_list,
    float* __restrict__ out)
{
    __shared__ unsigned char s_wlist[4][NN];

    const int tid   = threadIdx.x;
    const int wv    = __builtin_amdgcn_readfirstlane(tid >> 6);
    const int lane  = tid & 63;
    const int frame = blockIdx.y;
    const int tile  = blockIdx.x * 4 + wv;  // 0..255
    const int rp    = tile >> 2;            // row pair
    const int q     = tile & 3;             // x quarter

    // stage this wave's survivor list into its private LDS strip
    const unsigned char* lst = g_list + ((size_t)frame * 256 + tile) * NN;
    if (lane < NN / 4) {
        ((unsigned int*)&s_wlist[wv][0])[lane] = ((const unsigned int*)lst)[lane];
    }
    const int cnt = g_cnt[frame * 256 + tile]; // uniform -> s_load

    const int lx  = lane & 31, ly = lane >> 5;
    const int px  = q * 32 + lx;
    const int row = rp * 2 + ly;
    const float gy = (row + 0.5f) * (1.0f / HH);
    const float gx = (px  + 0.5f) * (1.0f / WW);
    const f2 gy2 = {gy, gy};
    const f2 gx2 = {gx, gx};
    const f2 lo2 = {-100.f, -100.f};

    const float* cfr = g_coef + (size_t)frame * (NN * COEF_STRIDE);

    float Tt = 1.f, rr = 0.f, gg = 0.f, bb = 0.f;
    bool live = true;
    int i = 0;

    // ---- pair loop: both slots' uniform loads issue together -> one
    //      lgkmcnt wait per PAIR; two independent qv chains (2x ILP) ----
    for (; i + 1 < cnt && live; i += 2) {
        int s0 = __builtin_amdgcn_readfirstlane((int)s_wlist[wv][i]);
        int s1 = __builtin_amdgcn_readfirstlane((int)s_wlist[wv][i + 1]);
        const float* c0 = cfr + s0 * COEF_STRIDE; // uniform -> s_loads
        const float* c1 = cfr + s1 * COEF_STRIDE;
        const f2* A0 = (const f2*)(c0);
        const f2* B0 = (const f2*)(c0 + 12);
        const f2* C0 = (const f2*)(c0 + 24);
        const f2* A1 = (const f2*)(c1);
        const f2* B1 = (const f2*)(c1 + 12);
        const f2* C1 = (const f2*)(c1 + 24);

        f2 qa = {1.f, 1.f}, qb = {1.f, 1.f};
        #pragma unroll
        for (int j = 0; j < 6; j++) {
            f2 ua = __builtin_elementwise_fma(B0[j], gx2,
                      __builtin_elementwise_fma(A0[j], gy2, C0[j]));
            f2 ub = __builtin_elementwise_fma(B1[j], gx2,
                      __builtin_elementwise_fma(A1[j], gy2, C1[j]));
            ua = __builtin_elementwise_max(ua, lo2);  // exp2 underflow guard
            ub = __builtin_elementwise_max(ub, lo2);  // (inf*0=NaN)
            f2 ea, eb;
            ea.x = __builtin_amdgcn_exp2f(ua.x);
            ea.y = __builtin_amdgcn_exp2f(ua.y);
            eb.x = __builtin_amdgcn_exp2f(ub.x);
            eb.y = __builtin_amdgcn_exp2f(ub.y);
            qa = __builtin_elementwise_fma(qa, ea, qa); // q *= 1 + 2^u
            qb = __builtin_elementwise_fma(qb, eb, qb);
        }
        float cov0 = __builtin_amdgcn_rcpf(qa.x * qa.y);
        float cov1 = __builtin_amdgcn_rcpf(qb.x * qb.y);
        float4 gca = *(const float4*)(c0 + 36);
        float4 gcb = *(const float4*)(c1 + 36);

        float a0 = cov0 * gca.x;
        float w0 = a0 * Tt;
        rr = fmaf(w0, gca.y, rr);
        gg = fmaf(w0, gca.z, gg);
        bb = fmaf(w0, gca.w, bb);
        Tt = fmaf(-a0, Tt, Tt);

        float a1 = cov1 * gcb.x;
        float w1 = a1 * Tt;
        rr = fmaf(w1, gcb.y, rr);
        gg = fmaf(w1, gcb.z, gg);
        bb = fmaf(w1, gcb.w, bb);
        Tt = fmaf(-a1, Tt, Tt);

        live = __any(Tt > 2e-3f);   // residual <= T < 2e-3
    }

    // ---- odd tail (single slot, R9 body) ----
    if (live && i < cnt) {
        int slot = __builtin_amdgcn_readfirstlane((int)s_wlist[wv][i]);
        const float* cf = cfr + slot * COEF_STRIDE;
        const f2* A2 = (const f2*)(cf);
        const f2* B2 = (const f2*)(cf + 12);
        const f2* C2 = (const f2*)(cf + 24);

        f2 qv = {1.f, 1.f};
        #pragma unroll
        for (int j = 0; j < 6; j++) {
            f2 u = __builtin_elementwise_fma(B2[j], gx2,
                     __builtin_elementwise_fma(A2[j], gy2, C2[j]));
            u = __builtin_elementwise_max(u, lo2);
            f2 e;
            e.x = __builtin_amdgcn_exp2f(u.x);
            e.y = __builtin_amdgcn_exp2f(u.y);
            qv = __builtin_elementwise_fma(qv, e, qv);
        }
        float cov = __builtin_amdgcn_rcpf(qv.x * qv.y);

        float a = cov * cf[36];
        float w = a * Tt;
        rr = fmaf(w, cf[37], rr);
        gg = fmaf(w, cf[38], gg);
        bb = fmaf(w, cf[39], bb);
        Tt = fmaf(-a, Tt, Tt);
    }

    size_t o = ((size_t)frame * (HH * WW) + (size_t)row * WW + px) * 3;
    *(F3*)(out + o) = F3{rr, gg, bb};    // coalesced dwordx3 per row segment
}

extern "C" void kernel_launch(void* const* d_in, const int* in_sizes, int n_in,
                              void* d_out, int out_size, void* d_ws, size_t ws_size,
                              hipStream_t stream) {
    const float* traj   = (const float*)d_in[0];
    const float* colors = (const float*)d_in[1];
    const float* alpha  = (const float*)d_in[2];
    const float* zval   = (const float*)d_in[3];
    const void*  csg    = d_in[4];
    float* out = (float*)d_out;

    const int T = in_sizes[0] / STATE_SZ; // 192

    size_t coef_sz = (size_t)T * NN * COEF_STRIDE * sizeof(float); // 3.93 MB
    size_t cnt_sz  = (size_t)T * 256 * sizeof(int);                // 0.20 MB
    float* g_coef = (float*)d_ws;
    int*   g_cnt  = (int*)((char*)d_ws + coef_sz);
    unsigned char* g_list = (unsigned char*)d_ws + coef_sz + cnt_sz; // 6.29 MB

    setup_kernel<<<T, STPB, 0, stream>>>(traj, colors, alpha, zval, csg,
                                         g_coef, g_cnt, g_list);
    dim3 grid(256 / 4, T); // 64 x 192, wave = one 32x2 tile
    raster_kernel<<<grid, RTPB, 0, stream>>>(g_coef, g_cnt, g_list, out);
}

// Round 6
// 196.909 us; speedup vs baseline: 1.5589x; 1.0582x over previous
//
#include <hip/hip_runtime.h>

// Soft differentiable rasterizer, forward only. Two-kernel structure.
// R14 -> R15 post-mortem: pair-batching neutral (131.9us = R9; 3rd null on
// load-latency theory). Revised model: slot-iter ~= 160cy = 96cy exp2
// (12 x 8cy wave64 quarter-rate, occupies issue) + ~64cy VALU/list
// overhead; 49152 waves x ~41 slots x 160cy / 1024 SIMD / 2.4GHz = 131us
// (matches 1%). Separately, E2E-raster "rest" correlates with WORKSPACE
// SIZE across rounds (10.4MB->73-77us, 29MB->118-120us, ~2.4us/MB):
// harness memsets workspace inside the timed window.
// R15: survivor BYTE LIST -> 128-BIT MASK per tile (16B).
// (a) ws 10.4 -> 4.7MB (drop g_list 6.3MB + g_cnt): predict -14us rest.
// (b) raster next-slot = s_ff1/s_and on SGPR mask: removes per-iter
//     ds_read_u8 + readfirstlane + lgkm wait; raster LDS = 0.
// (c) setup drops compaction + 32KB list copy (OR row-pair qbits, store
//     16B/tile, coalesced).
// Design (R8/R9): 32x2 px tiles, per-edge line-form interval cull,
// pos-first packing, packed-fp32 sigmoid product, front-to-back T,
// wave exit at T < 2e-3, slot order = z order (bit index ascending).

#define HH 128
#define WW 128
#define NN 128
#define KK 12
#define STPB 1024
#define RTPB 256
#define STATE_SZ (NN * KK * 2 + NN) // 3200
#define CULL_U 15.0f
#define COEF_STRIDE 40              // floats per slot: A[12] B[12] C[12] gc[4]
#define PQ_STRIDE 18                // float2 per slot (padded; 36 words)

typedef float f2 __attribute__((ext_vector_type(2)));

__global__ __launch_bounds__(STPB) void setup_kernel(
    const float* __restrict__ traj,
    const float* __restrict__ colors,
    const float* __restrict__ alpha,
    const float* __restrict__ zval,
    const void*  __restrict__ csg_raw,
    float* __restrict__ g_coef,               // [T][128][40]
    unsigned long long* __restrict__ g_mask)  // [T][256][2] 128-bit keep mask
{
    __shared__ __align__(16) float s_coef[NN][COEF_STRIDE];       // 20.5 KB
    __shared__ __align__(16) float2 s_pq[NN][PQ_STRIDE];          // 18 KB
    __shared__ float s_state[STATE_SZ];                           // 12.8 KB
    __shared__ float s_orient[NN];
    __shared__ float s_z[NN];
    __shared__ int   s_slot2prim[NN];
    __shared__ int   s_npos[NN], s_nneg[NN];
    __shared__ unsigned long long s_qbits[HH][4][2];              // 8 KB
    __shared__ int s_mode;

    const int frame = blockIdx.x;
    const int tid   = threadIdx.x;
    const float* st = traj + (size_t)frame * STATE_SZ;

    // ---- stage + csg layout detect (one-wave ballot) + counter init ----
    for (int i = tid; i < STATE_SZ; i += STPB) s_state[i] = st[i];
    if (tid < NN) { s_z[tid] = zval[tid]; s_npos[tid] = 0; s_nneg[tid] = 0; }
    if (tid < 64) {
        unsigned w = (tid < 32) ? ((const unsigned*)csg_raw)[tid] : 0u;
        unsigned long long anyw = __ballot(w > 1u);            // some word not 0/1
        unsigned long long anyb = __ballot((w & 0xFEFEFEFEu) != 0u); // some byte > 1
        if (tid == 0) s_mode = (anyw == 0ull) ? 0 : ((anyb == 0ull) ? 1 : 2);
    }
    __syncthreads();

    // ---- per-prim: orient, g = alpha*sigmoid(alive), z-rank -> slot ----
    if (tid < NN) {
        const int n = tid;
        float area2 = 0.f;
        #pragma unroll
        for (int k = 0; k < KK; k++) {
            int k1 = (k + 1) % KK;
            float v0x = s_state[(n * KK + k)  * 2 + 0];
            float v0y = s_state[(n * KK + k)  * 2 + 1];
            float v1x = s_state[(n * KK + k1) * 2 + 0];
            float v1y = s_state[(n * KK + k1) * 2 + 1];
            area2 += v0x * v1y - v1x * v0y;
        }
        float orient = (area2 > 0.f) ? 1.f : ((area2 < 0.f) ? -1.f : 0.f);
        s_orient[n] = orient;

        float alive = s_state[NN * KK * 2 + n];
        float g = alpha[n] / (1.f + __expf(-alive));

        float zn = s_z[n];
        int rank = 0;
        #pragma unroll 8
        for (int j = 0; j < NN; j++) {
            float zj = s_z[j];
            rank += (zj < zn || (zj == zn && j < n)) ? 1 : 0;
        }
        int slot = (NN - 1) - rank; // slot 0 = frontmost (largest z)
        s_slot2prim[slot] = n;

        int mode = s_mode;
        int sub;
        if (mode == 0)      sub = ((const int*)csg_raw)[n] != 0;
        else if (mode == 1) sub = ((const unsigned char*)csg_raw)[n] != 0;
        else                sub = ((const float*)csg_raw)[n] != 0.f;
        float cs = sub ? 0.f : 1.f;
        s_coef[slot][36] = g;
        s_coef[slot][37] = colors[n * 3 + 0] * cs;
        s_coef[slot][38] = colors[n * 3 + 1] * cs;
        s_coef[slot][39] = colors[n * 3 + 2] * cs;
    }
    __syncthreads();

    // ---- edge coefficients (slot-ordered SoA) ----
    const float QSCALE = 100.0f * 1.4426950408889634f;
    for (int idx = tid; idx < NN * KK; idx += STPB) {
        int slot = idx / KK;
        int k    = idx - slot * KK;
        int n    = s_slot2prim[slot];
        int k1   = (k + 1) % KK;
        float v0x = s_state[(n * KK + k)  * 2 + 0];
        float v0y = s_state[(n * KK + k)  * 2 + 1];
        float v1x = s_state[(n * KK + k1) * 2 + 0];
        float v1y = s_state[(n * KK + k1) * 2 + 1];
        float ex = v1x - v0x, ey = v1y - v0y;
        float q  = -s_orient[n] * QSCALE;
        s_coef[slot][0  + k] = q * ex;                      // A
        s_coef[slot][12 + k] = -q * ey;                     // B
        s_coef[slot][24 + k] = -q * (ex * v0y - ey * v0x);  // C
    }
    __syncthreads();

    // ---- line form per edge: x-constraint t(gy) = Q*gy + P ----
    // B>0: x <= t (+SLACK); B<0: x >= t (stored negated: -x <= -t, +SLACK);
    // B==0: no x-constraint -> neg-bucket entry with t' = +1e30 (never binds).
    // Pos edges packed first (k < npos). STRIDED LOOP (R8 bug: bare if).
    const float SLACK = 0.01f;
    for (int idx = tid; idx < NN * KK; idx += STPB) {
        int slot = idx / KK;
        int k    = idx - slot * KK;
        (void)k;
        float A = s_coef[slot][idx - slot * KK];
        float B = s_coef[slot][12 + (idx - slot * KK)];
        float C = s_coef[slot][24 + (idx - slot * KK)];
        float rcpB = __builtin_amdgcn_rcpf(B);
        float Praw = (CULL_U - C) * rcpB;
        float Qraw = -A * rcpB;
        if (B > 0.f) {
            int i = atomicAdd(&s_npos[slot], 1);
            s_pq[slot][i] = make_float2(Qraw, Praw + SLACK);
        } else if (B < 0.f) {
            int i = atomicAdd(&s_nneg[slot], 1);
            s_pq[slot][(KK - 1) - i] = make_float2(-Qraw, -Praw + SLACK);
        } else { // B == 0: x-independent edge; conservatively no constraint
            int i = atomicAdd(&s_nneg[slot], 1);
            s_pq[slot][(KK - 1) - i] = make_float2(0.f, 1e30f);
        }
    }
    __syncthreads();

    // ---- joint interval cull; 4 x-quarter keep masks per row ----
    // wave covers one row (r const) x 64 slots (s = s0 + lane).
    const float GX_LO = 0.5f / WW;
    const float GX_HI = (WW - 0.5f) / WW;
    for (int j = 0; j < (HH * NN) / STPB; j++) {     // 16 iters
        int idx = j * STPB + tid;
        int r = idx >> 7, s = idx & (NN - 1);
        float gyr = (r + 0.5f) * (1.0f / HH);
        int npos = s_npos[s];
        const float4* pq4 = (const float4*)&s_pq[s][0];
        float y1 = 1e30f, y2 = 1e30f;
        #pragma unroll
        for (int h = 0; h < KK / 2; h++) {
            float4 v = pq4[h];                       // {Q,P,Q,P}
            int k0 = 2 * h, k1 = 2 * h + 1;
            float t0 = fmaf(v.x, gyr, v.y);
            float t1 = fmaf(v.z, gyr, v.w);
            bool p0 = k0 < npos, p1 = k1 < npos;
            y1 = fminf(y1, p0 ? t0 : 1e30f);
            y2 = fminf(y2, p0 ? 1e30f : t0);
            y1 = fminf(y1, p1 ? t1 : 1e30f);
            y2 = fminf(y2, p1 ? 1e30f : t1);
        }
        float xhi = fminf(y1, GX_HI);
        float xlo = fmaxf(-y2, GX_LO);
        bool ne = (xlo <= xhi);
        #pragma unroll
        for (int q = 0; q < 4; q++) {
            float qlo = (q * 32 + 0.5f) * (1.0f / WW);
            float qhi = (q * 32 + 31.5f) * (1.0f / WW);
            unsigned long long m = __ballot(ne && (xlo <= qhi) && (xhi >= qlo));
            if ((tid & 63) == 0) s_qbits[r][q][(s >= 64) ? 1 : 0] = m;
        }
    }
    __syncthreads();

    // ---- mask output: OR row pairs, store 16B/tile (no compaction) ----
    if (tid < 512) {
        int t = tid >> 1, h = tid & 1;
        int rp = t >> 2, qq = t & 3;
        unsigned long long m = s_qbits[2 * rp][qq][h] | s_qbits[2 * rp + 1][qq][h];
        g_mask[((size_t)frame * 256 + t) * 2 + h] = m;
    }

    // ---- copy out coefficients ----
    {
        float4* dstc = (float4*)(g_coef + (size_t)frame * (NN * COEF_STRIDE));
        const float4* srcc = (const float4*)&s_coef[0][0];
        for (int i = tid; i < (NN * COEF_STRIDE) / 4; i += STPB) dstc[i] = srcc[i];
    }
}

struct F3 { float x, y, z; };

__global__ __launch_bounds__(RTPB) void raster_kernel(
    const float* __restrict__ g_coef,
    const unsigned long long* __restrict__ g_mask,
    float* __restrict__ out)
{
    const int tid   = threadIdx.x;
    const int wv    = __builtin_amdgcn_readfirstlane(tid >> 6);
    const int lane  = tid & 63;
    const int frame = blockIdx.y;
    const int tile  = blockIdx.x * 4 + wv;  // 0..255
    const int rp    = tile >> 2;            // row pair
    const int q     = tile & 3;             // x quarter

    // 128-bit survivor mask, forced to SGPRs (readfirstlane per 32b half)
    const unsigned long long* mp = g_mask + ((size_t)frame * 256 + tile) * 2;
    unsigned long long m0 = mp[0], m1 = mp[1];
    {
        unsigned lo0 = (unsigned)__builtin_amdgcn_readfirstlane((int)(unsigned)m0);
        unsigned hi0 = (unsigned)__builtin_amdgcn_readfirstlane((int)(unsigned)(m0 >> 32));
        unsigned lo1 = (unsigned)__builtin_amdgcn_readfirstlane((int)(unsigned)m1);
        unsigned hi1 = (unsigned)__builtin_amdgcn_readfirstlane((int)(unsigned)(m1 >> 32));
        m0 = ((unsigned long long)hi0 << 32) | lo0;
        m1 = ((unsigned long long)hi1 << 32) | lo1;
    }

    const int lx  = lane & 31, ly = lane >> 5;
    const int px  = q * 32 + lx;
    const int row = rp * 2 + ly;
    const float gy = (row + 0.5f) * (1.0f / HH);
    const float gx = (px  + 0.5f) * (1.0f / WW);
    const f2 gy2 = {gy, gy};
    const f2 gx2 = {gx, gx};
    const f2 lo2 = {-100.f, -100.f};

    const float* cfr = g_coef + (size_t)frame * (NN * COEF_STRIDE);

    float Tt = 1.f, rr = 0.f, gg = 0.f, bb = 0.f;
    bool live = true;

    // two scalar-mask loops: slots 0-63 (m0), 64-127 (m1); bit index
    // ascending = slot ascending = front-to-back z order.
    #pragma unroll
    for (int half = 0; half < 2; half++) {
        unsigned long long m = half ? m1 : m0;
        const int base = half << 6;
        while (m != 0ull && live) {
            int slot = base + __builtin_ctzll(m);   // uniform -> SALU ff1
            m &= m - 1ull;
            const float* cf = cfr + slot * COEF_STRIDE; // uniform -> s_loads
            const f2* A2 = (const f2*)(cf);
            const f2* B2 = (const f2*)(cf + 12);
            const f2* C2 = (const f2*)(cf + 24);

            f2 qv = {1.f, 1.f};
            #pragma unroll
            for (int j = 0; j < 6; j++) {
                f2 u = __builtin_elementwise_fma(B2[j], gx2,
                         __builtin_elementwise_fma(A2[j], gy2, C2[j]));
                u = __builtin_elementwise_max(u, lo2);   // exp2 underflow guard (inf*0=NaN)
                f2 e;
                e.x = __builtin_amdgcn_exp2f(u.x);
                e.y = __builtin_amdgcn_exp2f(u.y);
                qv = __builtin_elementwise_fma(qv, e, qv); // q *= 1 + 2^u
            }
            float cov = __builtin_amdgcn_rcpf(qv.x * qv.y);

            float a = cov * cf[36];
            float w = a * Tt;
            rr = fmaf(w, cf[37], rr);
            gg = fmaf(w, cf[38], gg);
            bb = fmaf(w, cf[39], bb);
            Tt = fmaf(-a, Tt, Tt);

            live = __any(Tt > 2e-3f);   // residual <= T < 2e-3
        }
    }

    size_t o = ((size_t)frame * (HH * WW) + (size_t)row * WW + px) * 3;
    *(F3*)(out + o) = F3{rr, gg, bb};    // coalesced dwordx3 per row segment
}

extern "C" void kernel_launch(void* const* d_in, const int* in_sizes, int n_in,
                              void* d_out, int out_size, void* d_ws, size_t ws_size,
                              hipStream_t stream) {
    const float* traj   = (const float*)d_in[0];
    const float* colors = (const float*)d_in[1];
    const float* alpha  = (const float*)d_in[2];
    const float* zval   = (const float*)d_in[3];
    const void*  csg    = d_in[4];
    float* out = (float*)d_out;

    const int T = in_sizes[0] / STATE_SZ; // 192

    size_t coef_sz = (size_t)T * NN * COEF_STRIDE * sizeof(float); // 3.93 MB
    float* g_coef = (float*)d_ws;
    unsigned long long* g_mask =
        (unsigned long long*)((char*)d_ws + coef_sz);              // 0.79 MB

    setup_kernel<<<T, STPB, 0, stream>>>(traj, colors, alpha, zval, csg,
                                         g_coef, g_mask);
    dim3 grid(256 / 4, T); // 64 x 192, wave = one 32x2 tile
    raster_kernel<<<grid, RTPB, 0, stream>>>(g_coef, g_mask, out);
}